// Round 1
// baseline (68.992 us; speedup 1.0000x reference)
//
#include <hip/hip_runtime.h>

// Shapes fixed by setup_inputs(): B=4, L=1024, A=5, KNN=32, K=16.
// Output: [B, L, KNN, A*A*K] f32 = 52,428,800 elements (209.7 MB) — write-bound.
constexpr int A_DIM  = 5;
constexpr int PAIRS  = 25;   // A*A
constexpr int K_DIM  = 16;
constexpr int KNN    = 32;
constexpr int L_DIM  = 1024; // power of 2 -> shift/mask decode
constexpr int B_DIM  = 4;
// 1/sqrt(2*3.1415926)  (reference uses pi literal 3.1415926)
constexpr float INV_SQRT_2PI = 0.39894228f;

__global__ __launch_bounds__(256) void gauss_rbf_kernel(
    const float* __restrict__ X,           // [B,L,A,3]
    const int*   __restrict__ E_idx,       // [B,L,KNN]
    const float* __restrict__ mask_atoms,  // [B,L,A]
    const float* __restrict__ mask_attend, // [B,L,KNN]
    const float* __restrict__ means,       // [K]
    const float* __restrict__ stds,        // [K]
    const float* __restrict__ mul,         // [A*A]
    const float* __restrict__ bias,        // [A*A]
    float* __restrict__ out)               // [B,L,KNN,A*A*K]
{
    const unsigned gid = blockIdx.x * 256u + threadIdx.x;   // one (edge, pair) per thread
    const unsigned e    = gid / PAIRS;                      // edge index: b*L*KNN + l*KNN + kn
    const int      pair = (int)(gid - e * PAIRS);
    const int      i    = pair / A_DIM;                     // neighbor atom
    const int      j    = pair - i * A_DIM;                 // center atom

    const unsigned bl = e >> 5;          // b*L + l   (KNN = 32)
    const unsigned b  = bl >> 10;        // L = 1024
    const int      n  = E_idx[e];        // neighbor residue
    const unsigned bn = (b << 10) | (unsigned)n;   // b*L + n

    // coordinates (X is tiny -> L1/L2 resident)
    const float* xn = X + ((size_t)bn * A_DIM + i) * 3;
    const float* xc = X + ((size_t)bl * A_DIM + j) * 3;
    const float dx = xn[0] - xc[0];
    const float dy = xn[1] - xc[1];
    const float dz = xn[2] - xc[2];
    const float D  = sqrtf(dx * dx + dy * dy + dz * dz);

    // mask_pair[i,j] = mask_na[i] * mask_na[j], BOTH gathered at neighbor residue
    const float mi = mask_atoms[(size_t)bn * A_DIM + i];
    const float mj = mask_atoms[(size_t)bn * A_DIM + j];

    // x = (mul*D + bias) * mask_pair  (mask applied BEFORE the RBF, per reference)
    const float x   = (mul[pair] * D + bias[pair]) * (mi * mj);
    const float att = mask_attend[e];

    float4 o[4];
    float* op = reinterpret_cast<float*>(o);
#pragma unroll
    for (int k = 0; k < K_DIM; ++k) {
        const float sd   = fabsf(stds[k]) + 0.01f;
        const float inv  = __builtin_amdgcn_rcpf(sd);          // ~1 ulp, threshold is 3.3e-2
        const float coef = inv * (INV_SQRT_2PI) * att;
        const float z    = (x - means[k]) * inv;
        op[k] = coef * __expf(-0.5f * z * z);
    }

    // 16 contiguous floats per thread -> 4x float4, wave writes contiguous 4 KB
    float4* dst = reinterpret_cast<float4*>(out) + (size_t)gid * 4;
    dst[0] = o[0];
    dst[1] = o[1];
    dst[2] = o[2];
    dst[3] = o[3];
}

extern "C" void kernel_launch(void* const* d_in, const int* in_sizes, int n_in,
                              void* d_out, int out_size, void* d_ws, size_t ws_size,
                              hipStream_t stream) {
    const float* X           = (const float*)d_in[0];
    const int*   E_idx       = (const int*)  d_in[1];
    const float* mask_atoms  = (const float*)d_in[2];
    const float* mask_attend = (const float*)d_in[3];
    const float* means       = (const float*)d_in[4];
    const float* stds        = (const float*)d_in[5];
    const float* mul         = (const float*)d_in[6];
    const float* bias        = (const float*)d_in[7];
    float*       out         = (float*)d_out;

    const int total  = B_DIM * L_DIM * KNN * PAIRS;  // 3,276,800 threads
    const int block  = 256;
    const int grid   = total / block;                // 12,800 (exact)

    gauss_rbf_kernel<<<grid, block, 0, stream>>>(
        X, E_idx, mask_atoms, mask_attend, means, stds, mul, bias, out);
}

// Round 2
// 48.147 us; speedup vs baseline: 1.4330x; 1.4330x over previous
//
#include <hip/hip_runtime.h>

// Shapes fixed by setup_inputs(): B=4, L=1024, A=5, KNN=32, K=16.
// Output: [B, L, KNN, A*A*K] f32 = 52,428,800 elements (209.7 MB) — write-bound.
// R1 lesson: per-thread 64B stores -> 64B-stride lanes per instruction -> 4x
// write-request amplification (69us vs ~30us floor). This version: 4 threads
// per (edge,pair), one float4 per thread, lane-contiguous stores.
constexpr int A_DIM  = 5;
constexpr int PAIRS  = 25;   // A*A
constexpr int K_DIM  = 16;
constexpr int KNN    = 32;
constexpr int L_DIM  = 1024;
constexpr int B_DIM  = 4;
// 1/sqrt(2*3.1415926)  (reference uses pi literal 3.1415926)
constexpr float INV_SQRT_2PI = 0.39894228f;

__global__ __launch_bounds__(256) void gauss_rbf_kernel(
    const float* __restrict__ X,           // [B,L,A,3]
    const int*   __restrict__ E_idx,       // [B,L,KNN]
    const float* __restrict__ mask_atoms,  // [B,L,A]
    const float* __restrict__ mask_attend, // [B,L,KNN]
    const float* __restrict__ means,       // [K]
    const float* __restrict__ stds,        // [K]
    const float* __restrict__ mul,         // [A*A]
    const float* __restrict__ bias,        // [A*A]
    float* __restrict__ out)               // [B,L,KNN,A*A*K]
{
    // Per-channel constants, computed once per block (removes per-thread rcp).
    __shared__ float s_inv[K_DIM], s_coef[K_DIM], s_mu[K_DIM];
    const int tid = threadIdx.x;
    if (tid < K_DIM) {
        const float sd  = fabsf(stds[tid]) + 0.01f;
        const float inv = __builtin_amdgcn_rcpf(sd);   // ~1 ulp; threshold 3.3e-2
        s_inv[tid]  = inv;
        s_coef[tid] = inv * INV_SQRT_2PI;
        s_mu[tid]   = means[tid];
    }
    __syncthreads();

    const unsigned gid = blockIdx.x * 256u + tid;  // one float4 (4 channels) per thread
    const unsigned q   = gid >> 2;                 // (edge, pair) id
    const int      c   = (int)(gid & 3u);          // channel quartet 0..3
    const unsigned e   = q / PAIRS;                // edge: b*L*KNN + l*KNN + kn
    const int      pair = (int)(q - e * PAIRS);
    const int      i   = pair / A_DIM;             // neighbor atom
    const int      j   = pair - i * A_DIM;         // center atom

    const unsigned bl = e >> 5;                    // b*L + l   (KNN = 32)
    const unsigned b  = bl >> 10;                  // L = 1024
    const int      n  = E_idx[e];                  // neighbor residue
    const unsigned bn = (b << 10) | (unsigned)n;   // b*L + n

    // coordinates (X is 245 KB -> L1/L2 resident; 4 consecutive lanes share addrs)
    const float* xn = X + ((size_t)bn * A_DIM + i) * 3;
    const float* xc = X + ((size_t)bl * A_DIM + j) * 3;
    const float dx = xn[0] - xc[0];
    const float dy = xn[1] - xc[1];
    const float dz = xn[2] - xc[2];
    const float D  = sqrtf(dx * dx + dy * dy + dz * dz);

    // mask_pair[i,j] = mask_na[i] * mask_na[j], BOTH gathered at neighbor residue
    const float mi = mask_atoms[(size_t)bn * A_DIM + i];
    const float mj = mask_atoms[(size_t)bn * A_DIM + j];

    // x = (mul*D + bias) * mask_pair  (mask applied BEFORE the RBF, per reference)
    const float x   = (mul[pair] * D + bias[pair]) * (mi * mj);
    const float att = mask_attend[e];

    float4 o;
    float* op = &o.x;
    const int k0 = c * 4;
#pragma unroll
    for (int t = 0; t < 4; ++t) {
        const int   k = k0 + t;
        const float z = (x - s_mu[k]) * s_inv[k];
        op[t] = (s_coef[k] * att) * __expf(-0.5f * z * z);
    }

    // lane-contiguous float4 stores: wave writes one contiguous 1 KB per instr
    reinterpret_cast<float4*>(out)[gid] = o;
}

extern "C" void kernel_launch(void* const* d_in, const int* in_sizes, int n_in,
                              void* d_out, int out_size, void* d_ws, size_t ws_size,
                              hipStream_t stream) {
    const float* X           = (const float*)d_in[0];
    const int*   E_idx       = (const int*)  d_in[1];
    const float* mask_atoms  = (const float*)d_in[2];
    const float* mask_attend = (const float*)d_in[3];
    const float* means       = (const float*)d_in[4];
    const float* stds        = (const float*)d_in[5];
    const float* mul         = (const float*)d_in[6];
    const float* bias        = (const float*)d_in[7];
    float*       out         = (float*)d_out;

    const int total  = B_DIM * L_DIM * KNN * PAIRS * 4;  // 13,107,200 threads
    const int block  = 256;
    const int grid   = total / block;                    // 51,200 (exact)

    gauss_rbf_kernel<<<grid, block, 0, stream>>>(
        X, E_idx, mask_atoms, mask_attend, means, stds, mul, bias, out);
}

// Round 4
// 46.195 us; speedup vs baseline: 1.4935x; 1.0423x over previous
//
#include <hip/hip_runtime.h>

// Shapes fixed by setup_inputs(): B=4, L=1024, A=5, KNN=32, K=16.
// Output: [B, L, KNN, A*A*K] f32 = 52,428,800 elements (209.7 MB) — write-bound.
// R1: per-thread 64B stores -> 4x write-request amplification (69us).
// R2: lane-contiguous float4 stores -> 48us; still 65% of 6.8 TB/s write floor.
// R3: nontemporal needs a NATIVE clang vector type, not HIP_vector_type.
// R4: 4 f32x4/thread (4x fewer waves), consts precomputed to d_ws, nt stores.
constexpr int A_DIM  = 5;
constexpr int PAIRS  = 25;   // A*A
constexpr int KNN    = 32;
constexpr int L_DIM  = 1024;
constexpr int B_DIM  = 4;
// 1/sqrt(2*3.1415926)  (reference uses pi literal 3.1415926)
constexpr float INV_SQRT_2PI = 0.39894228f;

typedef float f32x4 __attribute__((ext_vector_type(4)));

// d_ws layout (floats): [0..15] = means, [16..31] = 1/(|std|+0.01),
// [32..47] = inv * INV_SQRT_2PI.
__global__ __launch_bounds__(64) void setup_consts(
    const float* __restrict__ means, const float* __restrict__ stds,
    float* __restrict__ ws)
{
    const int k = threadIdx.x;
    if (k < 16) {
        const float sd  = fabsf(stds[k]) + 0.01f;
        const float inv = __builtin_amdgcn_rcpf(sd);   // ~1 ulp; threshold 3.3e-2
        ws[k]      = means[k];
        ws[16 + k] = inv;
        ws[32 + k] = inv * INV_SQRT_2PI;
    }
}

__global__ __launch_bounds__(256) void gauss_rbf_kernel(
    const float*  __restrict__ X,           // [B,L,A,3]
    const int*    __restrict__ E_idx,       // [B,L,KNN]
    const float*  __restrict__ mask_atoms,  // [B,L,A]
    const float*  __restrict__ mask_attend, // [B,L,KNN]
    const float*  __restrict__ mul,         // [A*A]
    const float*  __restrict__ bias,        // [A*A]
    const f32x4*  __restrict__ cst,         // d_ws: 12 f32x4s
    f32x4*        __restrict__ out4)        // [B*L*KNN*100] f32x4s
{
    const int tid = threadIdx.x;
    const int c   = tid & 3;                // channel quartet — constant across iters
    const f32x4 mu4 = cst[c];
    const f32x4 iv4 = cst[4 + c];
    const f32x4 co4 = cst[8 + c];

    unsigned fbase = blockIdx.x * 1024u + (unsigned)tid;

#pragma unroll
    for (int u = 0; u < 4; ++u) {
        const unsigned fidx = fbase + u * 256u;   // f32x4 index
        const unsigned q    = fidx >> 2;          // (edge, pair) id
        const unsigned e    = q / PAIRS;          // edge: b*L*KNN + l*KNN + kn
        const int      pair = (int)(q - e * PAIRS);
        const int      i    = pair / A_DIM;       // neighbor atom
        const int      j    = pair - i * A_DIM;   // center atom

        const unsigned bl = e >> 5;               // b*L + l   (KNN = 32)
        const unsigned b  = bl >> 10;             // L = 1024
        const int      n  = E_idx[e];             // neighbor residue
        const unsigned bn = (b << 10) | (unsigned)n;

        // near-uniform L1/L2-resident gathers (a wave spans 1-2 edges)
        const float* xn = X + ((size_t)bn * A_DIM + i) * 3;
        const float* xc = X + ((size_t)bl * A_DIM + j) * 3;
        const float dx = xn[0] - xc[0];
        const float dy = xn[1] - xc[1];
        const float dz = xn[2] - xc[2];
        const float D  = sqrtf(dx * dx + dy * dy + dz * dz);

        const float mi = mask_atoms[(size_t)bn * A_DIM + i];
        const float mj = mask_atoms[(size_t)bn * A_DIM + j];

        const float x   = (mul[pair] * D + bias[pair]) * (mi * mj);
        const float att = mask_attend[e];

        f32x4 o;
        {
            const float z0 = (x - mu4.x) * iv4.x;
            const float z1 = (x - mu4.y) * iv4.y;
            const float z2 = (x - mu4.z) * iv4.z;
            const float z3 = (x - mu4.w) * iv4.w;
            o.x = (co4.x * att) * __expf(-0.5f * z0 * z0);
            o.y = (co4.y * att) * __expf(-0.5f * z1 * z1);
            o.z = (co4.z * att) * __expf(-0.5f * z2 * z2);
            o.w = (co4.w * att) * __expf(-0.5f * z3 * z3);
        }

        // streaming store: lane-contiguous 1 KB/instr, nt = no cache allocate
        __builtin_nontemporal_store(o, &out4[fidx]);
    }
}

extern "C" void kernel_launch(void* const* d_in, const int* in_sizes, int n_in,
                              void* d_out, int out_size, void* d_ws, size_t ws_size,
                              hipStream_t stream) {
    const float* X           = (const float*)d_in[0];
    const int*   E_idx       = (const int*)  d_in[1];
    const float* mask_atoms  = (const float*)d_in[2];
    const float* mask_attend = (const float*)d_in[3];
    const float* means       = (const float*)d_in[4];
    const float* stds        = (const float*)d_in[5];
    const float* mul         = (const float*)d_in[6];
    const float* bias        = (const float*)d_in[7];
    float*       ws          = (float*)d_ws;
    f32x4*       out4        = (f32x4*)d_out;

    setup_consts<<<1, 64, 0, stream>>>(means, stds, ws);

    const int total_f4 = B_DIM * L_DIM * KNN * PAIRS * 4;  // 13,107,200 f32x4s
    const int grid     = total_f4 / 1024;                  // 12,800 blocks (exact)

    gauss_rbf_kernel<<<grid, 256, 0, stream>>>(
        X, E_idx, mask_atoms, mask_attend, mul, bias,
        (const f32x4*)ws, out4);
}